// Round 5
// baseline (238.918 us; speedup 1.0000x reference)
//
#include <hip/hip_runtime.h>
#include <hip/hip_bf16.h>

#define N_LIG 100000
#define N_TGT 4000
#define NEDGE 150000
#define DT 1280
#define HD 128
#define CAP_L 32
#define CAP_T 128

typedef __attribute__((ext_vector_type(8))) short short8v;
typedef __attribute__((ext_vector_type(4))) float f32x4;

static __device__ __forceinline__ ushort f2bf(float f) {
    __hip_bfloat16 h = __float2bfloat16(f);
    union { __hip_bfloat16 h; ushort u; } c; c.h = h; return c.u;
}
static __device__ __forceinline__ float bf2f(ushort u) {
    union { unsigned v; float f; } c; c.v = ((unsigned)u) << 16; return c.f;
}

// ---------------------------------------------------------------------------
// K1: build adjacency buckets (int atomics only).
// ---------------------------------------------------------------------------
__global__ __launch_bounds__(256) void k_fill(
    const int* __restrict__ src, const int* __restrict__ dst,
    int* __restrict__ cnt_src, int* __restrict__ cnt_dst,
    int* __restrict__ bsrc, int* __restrict__ bdst)
{
    int e = blockIdx.x * 256 + threadIdx.x;
    if (e >= NEDGE) return;
    int s = src[e], d = dst[e];
    int ps = atomicAdd(&cnt_src[s], 1);
    if (ps < CAP_L) bsrc[(size_t)s * CAP_L + ps] = d;
    int pd = atomicAdd(&cnt_dst[d], 1);
    if (pd < CAP_T) bdst[(size_t)d * CAP_T + pd] = s;
}

// ---------------------------------------------------------------------------
// K1b: Wt[n][k] = bf16(W2tl_r[k][n])  (B operand for k_pl)
// ---------------------------------------------------------------------------
__global__ __launch_bounds__(256) void k_prep(
    const float* __restrict__ W, ushort* __restrict__ Wt)
{
    int t = blockIdx.x * 256 + threadIdx.x;   // 16384
    int n = t >> 7, k = t & 127;
    Wt[(size_t)n * HD + k] = f2bf(W[(size_t)k * HD + n]);
}

// ---------------------------------------------------------------------------
// K1c: Wt1[n][k] bf16, n in [0,256): n<128 -> W1lt_r[:,n], else W1tl_l[:,n-128]
// ---------------------------------------------------------------------------
__global__ __launch_bounds__(256) void k_prep1(
    const float* __restrict__ Wr,   // W1lt_r [1280,128]
    const float* __restrict__ Wl,   // W1tl_l [1280,128]
    ushort* __restrict__ Wt1)       // [256,1280]
{
    __shared__ float lr[16][HD];
    __shared__ float ll[16][HD];
    int k0 = blockIdx.x * 16;
    for (int i = threadIdx.x; i < 16 * HD; i += 256) {
        int kk = i >> 7, n = i & 127;
        lr[kk][n] = Wr[(size_t)(k0 + kk) * HD + n];
        ll[kk][n] = Wl[(size_t)(k0 + kk) * HD + n];
    }
    __syncthreads();
    int n = threadIdx.x;
    int nn = n & 127;
    ushort tmp[16];
    if (n < HD) {
#pragma unroll
        for (int kk = 0; kk < 16; ++kk) tmp[kk] = f2bf(lr[kk][nn]);
    } else {
#pragma unroll
        for (int kk = 0; kk < 16; ++kk) tmp[kk] = f2bf(ll[kk][nn]);
    }
    *reinterpret_cast<uint4*>(Wt1 + (size_t)n * DT + k0)     = *reinterpret_cast<uint4*>(tmp);
    *reinterpret_cast<uint4*>(Wt1 + (size_t)n * DT + k0 + 8) = *reinterpret_cast<uint4*>(tmp + 8);
}

// ---------------------------------------------------------------------------
// K1d: m_t[t][0..3] = mean_{src in bucket} x_l[src]
// ---------------------------------------------------------------------------
__global__ __launch_bounds__(256) void k_mt(
    const float* __restrict__ xl,
    const int* __restrict__ bdst, const int* __restrict__ cnt_dst,
    float* __restrict__ m_t)
{
    int t = blockIdx.x * 256 + threadIdx.x;
    int row = t >> 3, lane8 = t & 7;
    if (row >= N_TGT) return;
    int deg = cnt_dst[row];
    int n = min(deg, CAP_T);
    float4 acc = make_float4(0.f, 0.f, 0.f, 0.f);
    for (int i = lane8; i < n; i += 8) {
        int sid = bdst[(size_t)row * CAP_T + i];
        float4 x = *reinterpret_cast<const float4*>(xl + 4ull * (unsigned)sid);
        acc.x += x.x; acc.y += x.y; acc.z += x.z; acc.w += x.w;
    }
#pragma unroll
    for (int off = 1; off < 8; off <<= 1) {
        acc.x += __shfl_xor(acc.x, off); acc.y += __shfl_xor(acc.y, off);
        acc.z += __shfl_xor(acc.z, off); acc.w += __shfl_xor(acc.w, off);
    }
    if (lane8 == 0) {
        float dinv = 1.0f / fmaxf((float)deg, 1.0f);
        float4 o = make_float4(acc.x * dinv, acc.y * dinv, acc.z * dinv, acc.w * dinv);
        *reinterpret_cast<float4*>(m_t + 4 * row) = o;
    }
}

// ---------------------------------------------------------------------------
// K2: MFMA target conv1.  D = x_t(bf16 on the fly) @ Wt1^T
// ---------------------------------------------------------------------------
__global__ __launch_bounds__(256) void k_tgt1m(
    const float* __restrict__ xt,     // [4000,1280] f32
    const ushort* __restrict__ Wt1,   // [256,1280] bf16
    const float* __restrict__ m_t,    // [4000,4]
    const float* __restrict__ W1lt_l, // [4,128]
    const float* __restrict__ b1lt,
    float* __restrict__ h_t, float* __restrict__ y_t1)
{
    int w = threadIdx.x >> 6;
    int lane = threadIdx.x & 63;
    int l15 = lane & 15, g = lane >> 4;
    int row0 = blockIdx.x * 16;
    int cb = w * 64;

    const float* aptr = xt + (size_t)(row0 + l15) * DT;

    f32x4 acc[4];
#pragma unroll
    for (int ct = 0; ct < 4; ++ct) acc[ct] = (f32x4){0.f, 0.f, 0.f, 0.f};

    for (int ks = 0; ks < DT / 32; ++ks) {
        int kb = ks * 32 + g * 4;
        float4 a0 = *reinterpret_cast<const float4*>(aptr + kb);
        float4 a1 = *reinterpret_cast<const float4*>(aptr + kb + 16);
        union { ushort us[8]; short8v s; } ua;
        ua.us[0] = f2bf(a0.x); ua.us[1] = f2bf(a0.y); ua.us[2] = f2bf(a0.z); ua.us[3] = f2bf(a0.w);
        ua.us[4] = f2bf(a1.x); ua.us[5] = f2bf(a1.y); ua.us[6] = f2bf(a1.z); ua.us[7] = f2bf(a1.w);
#pragma unroll
        for (int ct = 0; ct < 4; ++ct) {
            const ushort* bp = Wt1 + (size_t)(cb + ct * 16 + l15) * DT + kb;
            uint2 b0 = *reinterpret_cast<const uint2*>(bp);
            uint2 b1 = *reinterpret_cast<const uint2*>(bp + 16);
            union { uint4 u; short8v s; } ub;
            ub.u = make_uint4(b0.x, b0.y, b1.x, b1.y);
            acc[ct] = __builtin_amdgcn_mfma_f32_16x16x32_bf16(ua.s, ub.s, acc[ct], 0, 0, 0);
        }
    }

    if (w < 2) {
#pragma unroll
        for (int ct = 0; ct < 4; ++ct) {
            int c = cb + ct * 16 + l15;
            float wl0 = W1lt_l[c], wl1 = W1lt_l[HD + c],
                  wl2 = W1lt_l[2 * HD + c], wl3 = W1lt_l[3 * HD + c];
            float bb = b1lt[c];
#pragma unroll
            for (int j = 0; j < 4; ++j) {
                int grow = row0 + 4 * g + j;
                float4 m = *reinterpret_cast<const float4*>(m_t + 4 * grow);
                float v = acc[ct][j] + bb + m.x * wl0 + m.y * wl1 + m.z * wl2 + m.w * wl3;
                h_t[(size_t)grow * HD + c] = fmaxf(v, 0.0f);
            }
        }
    } else {
#pragma unroll
        for (int ct = 0; ct < 4; ++ct) {
            int c = cb - HD + ct * 16 + l15;
#pragma unroll
            for (int j = 0; j < 4; ++j) {
                int grow = row0 + 4 * g + j;
                y_t1[(size_t)grow * HD + c] = acc[ct][j];
            }
        }
    }
}

// ---------------------------------------------------------------------------
// K3: fused ligand conv1 -> h_l in bf16
// ---------------------------------------------------------------------------
__global__ __launch_bounds__(256) void k_hl(
    const float* __restrict__ xl, const float* __restrict__ y_t1,
    const int* __restrict__ bsrc, const int* __restrict__ cnt_src,
    const float* __restrict__ W1tl_r,  // [4,128]
    const float* __restrict__ b1tl,
    ushort* __restrict__ hlb)
{
    int t = blockIdx.x * 256 + threadIdx.x;
    int node = t >> 5;
    int c = t & 31;
    if (node >= N_LIG) return;
    int deg = cnt_src[node];
    int n = min(deg, CAP_L);
    float4 s = make_float4(0.f, 0.f, 0.f, 0.f);
    for (int i = 0; i < n; ++i) {
        int did = bsrc[(size_t)node * CAP_L + i];
        float4 v = *reinterpret_cast<const float4*>(y_t1 + (size_t)did * HD + c * 4);
        s.x += v.x; s.y += v.y; s.z += v.z; s.w += v.w;
    }
    float dinv = 1.0f / fmaxf((float)deg, 1.0f);
    float4 x  = *reinterpret_cast<const float4*>(xl + 4ull * (unsigned)node);
    float4 b4 = *reinterpret_cast<const float4*>(b1tl + c * 4);
    float4 w0 = *reinterpret_cast<const float4*>(W1tl_r + 0 * HD + c * 4);
    float4 w1 = *reinterpret_cast<const float4*>(W1tl_r + 1 * HD + c * 4);
    float4 w2 = *reinterpret_cast<const float4*>(W1tl_r + 2 * HD + c * 4);
    float4 w3 = *reinterpret_cast<const float4*>(W1tl_r + 3 * HD + c * 4);
    ushort4 o;
    o.x = f2bf(fmaxf(s.x * dinv + b4.x + x.x * w0.x + x.y * w1.x + x.z * w2.x + x.w * w3.x, 0.f));
    o.y = f2bf(fmaxf(s.y * dinv + b4.y + x.x * w0.y + x.y * w1.y + x.z * w2.y + x.w * w3.y, 0.f));
    o.z = f2bf(fmaxf(s.z * dinv + b4.z + x.x * w0.z + x.y * w1.z + x.z * w2.z + x.w * w3.z, 0.f));
    o.w = f2bf(fmaxf(s.w * dinv + b4.w + x.x * w0.w + x.y * w1.w + x.z * w2.w + x.w * w3.w, 0.f));
    *reinterpret_cast<ushort4*>(hlb + (size_t)node * HD + c * 4) = o;
}

// ---------------------------------------------------------------------------
// K4: h_t [4000,128] @ {W2tl_l, W2lt_r} -> y_t2, htW2r
// ---------------------------------------------------------------------------
__global__ __launch_bounds__(256) void k_tgt_gemm2(
    const float* __restrict__ ht,
    const float* __restrict__ Wl,   // W2tl_l [128,128]
    const float* __restrict__ Wr,   // W2lt_r [128,128]
    float* __restrict__ y_t2,
    float* __restrict__ htW2r)
{
    __shared__ float xs[8][HD];
    int row0 = blockIdx.x * 8;
    const float4* srcv = reinterpret_cast<const float4*>(ht + (size_t)row0 * HD);
    float4* dstv = reinterpret_cast<float4*>(&xs[0][0]);
    for (int i = threadIdx.x; i < 8 * HD / 4; i += 256) dstv[i] = srcv[i];
    __syncthreads();

    int n = threadIdx.x;
    const float* W = (n < HD) ? (Wl + n) : (Wr + (n - HD));
    float acc[8] = {0.f,0.f,0.f,0.f,0.f,0.f,0.f,0.f};
    for (int k = 0; k < HD; k += 4) {
        float w0 = W[(size_t)(k + 0) * HD];
        float w1 = W[(size_t)(k + 1) * HD];
        float w2 = W[(size_t)(k + 2) * HD];
        float w3 = W[(size_t)(k + 3) * HD];
#pragma unroll
        for (int r = 0; r < 8; ++r) {
            float4 a = *reinterpret_cast<const float4*>(&xs[r][k]);
            acc[r] += a.x * w0 + a.y * w1 + a.z * w2 + a.w * w3;
        }
    }
    float* o = (n < HD) ? (y_t2 + (size_t)row0 * HD + n)
                        : (htW2r + (size_t)row0 * HD + (n - HD));
#pragma unroll
    for (int r = 0; r < 8; ++r) o[(size_t)r * HD] = acc[r];
}

// ---------------------------------------------------------------------------
// K4b: gl2[l] = bf16( mean_{dst in bucket} y_t2[dst] )   (k_hl-style gather)
// ---------------------------------------------------------------------------
__global__ __launch_bounds__(256) void k_gl(
    const float* __restrict__ y_t2,
    const int* __restrict__ bsrc, const int* __restrict__ cnt_src,
    ushort* __restrict__ gl2)
{
    int t = blockIdx.x * 256 + threadIdx.x;
    int node = t >> 5;
    int c = t & 31;
    if (node >= N_LIG) return;
    int deg = cnt_src[node];
    int n = min(deg, CAP_L);
    float4 s = make_float4(0.f, 0.f, 0.f, 0.f);
    for (int i = 0; i < n; ++i) {
        int did = bsrc[(size_t)node * CAP_L + i];
        float4 v = *reinterpret_cast<const float4*>(y_t2 + (size_t)did * HD + c * 4);
        s.x += v.x; s.y += v.y; s.z += v.z; s.w += v.w;
    }
    float dinv = 1.0f / fmaxf((float)deg, 1.0f);
    ushort4 o;
    o.x = f2bf(s.x * dinv); o.y = f2bf(s.y * dinv);
    o.z = f2bf(s.z * dinv); o.w = f2bf(s.w * dinv);
    *reinterpret_cast<ushort4*>(gl2 + (size_t)node * HD + c * 4) = o;
}

// ---------------------------------------------------------------------------
// K5: fused target conv2 + predictor — two-phase gather (8x32-lane groups,
// ushort4 row loads, LDS reduce), then 128-thread GEMM column phase.
// ---------------------------------------------------------------------------
__global__ __launch_bounds__(256) void k_pt(
    const ushort* __restrict__ hlb,
    const int* __restrict__ bdst, const int* __restrict__ cnt_dst,
    const float* __restrict__ W,    // W2lt_l [128,128]
    const float* __restrict__ b,    // b2lt
    const float* __restrict__ htW2r,
    const float* __restrict__ Wp,   // [256]
    float* __restrict__ p_t)
{
    __shared__ float sm[8][HD];
    __shared__ float msh[HD];
    __shared__ float sum2[2];
    int row = blockIdx.x;
    int wg = threadIdx.x >> 5, c = threadIdx.x & 31;
    int deg = cnt_dst[row];
    int nn = min(deg, CAP_T);

    float4 s = make_float4(0.f, 0.f, 0.f, 0.f);
    for (int i = wg; i < nn; i += 8) {
        int sid = bdst[(size_t)row * CAP_T + i];
        ushort4 v = *reinterpret_cast<const ushort4*>(hlb + (size_t)sid * HD + c * 4);
        s.x += bf2f(v.x); s.y += bf2f(v.y); s.z += bf2f(v.z); s.w += bf2f(v.w);
    }
    *reinterpret_cast<float4*>(&sm[wg][c * 4]) = s;
    __syncthreads();

    if (threadIdx.x < HD) {
        int h = threadIdx.x;
        float dinv = 1.0f / fmaxf((float)deg, 1.0f);
        float acc = sm[0][h] + sm[1][h] + sm[2][h] + sm[3][h]
                  + sm[4][h] + sm[5][h] + sm[6][h] + sm[7][h];
        msh[h] = acc * dinv;
    }
    __syncthreads();

    if (threadIdx.x < HD) {
        int h = threadIdx.x;
        float g = 0.f;
        for (int k = 0; k < HD; k += 4) {
            float4 mk = *reinterpret_cast<const float4*>(&msh[k]);
            g += mk.x * W[(size_t)(k + 0) * HD + h] + mk.y * W[(size_t)(k + 1) * HD + h]
               + mk.z * W[(size_t)(k + 2) * HD + h] + mk.w * W[(size_t)(k + 3) * HD + h];
        }
        float v = fmaxf(g + b[h] + htW2r[(size_t)row * HD + h], 0.0f);
        float part = v * Wp[HD + h];
#pragma unroll
        for (int off = 1; off < 64; off <<= 1) part += __shfl_xor(part, off);
        if ((h & 63) == 0) sum2[h >> 6] = part;
    }
    __syncthreads();
    if (threadIdx.x == 0) p_t[row] = sum2[0] + sum2[1];
}

// ---------------------------------------------------------------------------
// K6: ligand conv2 + predictor via MFMA — pure streaming now.
//   p_l = relu(hlb @ Wt^T + gl2 + b2tl) . wp_l
// ---------------------------------------------------------------------------
__global__ __launch_bounds__(256) void k_pl(
    const ushort* __restrict__ hlb,   // [N_LIG,128] bf16
    const ushort* __restrict__ Wt,    // [128 n][128 k] bf16
    const ushort* __restrict__ gl2,   // [N_LIG,128] bf16 (already mean)
    const float* __restrict__ b,      // b2tl
    const float* __restrict__ Wp,     // [256]; ligand part = Wp[0..127]
    float* __restrict__ p_l)
{
    int wid = threadIdx.x >> 6;
    int lane = threadIdx.x & 63;
    int l15 = lane & 15, g = lane >> 4;
    int wrow0 = blockIdx.x * 64 + wid * 16;

    f32x4 acc[8];
#pragma unroll
    for (int ct = 0; ct < 8; ++ct) acc[ct] = (f32x4){0.f, 0.f, 0.f, 0.f};

    int arow = wrow0 + l15;
    if (arow >= N_LIG) arow = N_LIG - 1;
    const ushort* aptr = hlb + (size_t)arow * HD;

#pragma unroll
    for (int ks = 0; ks < 4; ++ks) {
        int kb = ks * 32 + g * 4;
        uint2 a0 = *reinterpret_cast<const uint2*>(aptr + kb);
        uint2 a1 = *reinterpret_cast<const uint2*>(aptr + kb + 16);
        union { uint4 u; short8v s; } ua;
        ua.u = make_uint4(a0.x, a0.y, a1.x, a1.y);
#pragma unroll
        for (int ct = 0; ct < 8; ++ct) {
            const ushort* bp = Wt + (size_t)(ct * 16 + l15) * HD + kb;
            uint2 b0 = *reinterpret_cast<const uint2*>(bp);
            uint2 b1 = *reinterpret_cast<const uint2*>(bp + 16);
            union { uint4 u; short8v s; } ub;
            ub.u = make_uint4(b0.x, b0.y, b1.x, b1.y);
            acc[ct] = __builtin_amdgcn_mfma_f32_16x16x32_bf16(ua.s, ub.s, acc[ct], 0, 0, 0);
        }
    }

    float wpv[8], bv[8];
#pragma unroll
    for (int ct = 0; ct < 8; ++ct) {
        int c = ct * 16 + l15;
        wpv[ct] = Wp[c];
        bv[ct]  = b[c];
    }

#pragma unroll
    for (int j = 0; j < 4; ++j) {
        int row = wrow0 + g * 4 + j;
        bool valid = row < N_LIG;
        int lrow = valid ? row : (N_LIG - 1);
        const ushort* gp = gl2 + (size_t)lrow * HD + l15;
        float part = 0.f;
#pragma unroll
        for (int ct = 0; ct < 8; ++ct) {
            float v = acc[ct][j] + bf2f(gp[ct * 16]) + bv[ct];
            part += fmaxf(v, 0.f) * wpv[ct];
        }
#pragma unroll
        for (int off = 1; off < 16; off <<= 1) part += __shfl_xor(part, off);
        if (valid && l15 == 0) p_l[row] = part;
    }
}

// ---------------------------------------------------------------------------
// K7: out[e] = p_l[src[e]] + p_t[dst[e]] + bp
// ---------------------------------------------------------------------------
__global__ __launch_bounds__(256) void k_out(
    const int* __restrict__ src, const int* __restrict__ dst,
    const float* __restrict__ p_l, const float* __restrict__ p_t,
    const float* __restrict__ bp, float* __restrict__ out)
{
    int e = blockIdx.x * 256 + threadIdx.x;
    if (e >= NEDGE) return;
    out[e] = p_l[src[e]] + p_t[dst[e]] + bp[0];
}

// ---------------------------------------------------------------------------
extern "C" void kernel_launch(void* const* d_in, const int* in_sizes, int n_in,
                              void* d_out, int out_size, void* d_ws, size_t ws_size,
                              hipStream_t stream)
{
    const float* x_l    = (const float*)d_in[0];
    const float* x_t    = (const float*)d_in[1];
    const int*   ei     = (const int*)  d_in[2];
    const float* W1lt_l = (const float*)d_in[3];
    const float* b1lt   = (const float*)d_in[4];
    const float* W1lt_r = (const float*)d_in[5];
    const float* W1tl_l = (const float*)d_in[6];
    const float* b1tl   = (const float*)d_in[7];
    const float* W1tl_r = (const float*)d_in[8];
    const float* W2lt_l = (const float*)d_in[9];
    const float* b2lt   = (const float*)d_in[10];
    const float* W2lt_r = (const float*)d_in[11];
    const float* W2tl_l = (const float*)d_in[12];
    const float* b2tl   = (const float*)d_in[13];
    const float* W2tl_r = (const float*)d_in[14];
    const float* Wp     = (const float*)d_in[15];
    const float* bp     = (const float*)d_in[16];

    const int* src = ei;            // ligand indices
    const int* dst = ei + NEDGE;    // target indices

    char* ws = (char*)d_ws;
    size_t o = 0;
    int* cnt_src = (int*)(ws + o); o += (size_t)N_LIG * 4;
    int* cnt_dst = (int*)(ws + o); o += (size_t)N_TGT * 4;
    size_t zero_bytes = o;
    int* bsrc = (int*)(ws + o); o += (size_t)N_LIG * CAP_L * 4;
    int* bdst = (int*)(ws + o); o += (size_t)N_TGT * CAP_T * 4;
    ushort* hlb  = (ushort*)(ws + o); o += (size_t)N_LIG * HD * 2;
    ushort* gl2  = (ushort*)(ws + o); o += (size_t)N_LIG * HD * 2;
    ushort* Wt   = (ushort*)(ws + o); o += (size_t)HD * HD * 2;
    ushort* Wt1  = (ushort*)(ws + o); o += (size_t)256 * DT * 2;
    float* m_t   = (float*)(ws + o); o += (size_t)N_TGT * 4 * 4;
    float* y_t1  = (float*)(ws + o); o += (size_t)N_TGT * HD * 4;
    float* h_t   = (float*)(ws + o); o += (size_t)N_TGT * HD * 4;
    float* y_t2  = (float*)(ws + o); o += (size_t)N_TGT * HD * 4;
    float* htW2r = (float*)(ws + o); o += (size_t)N_TGT * HD * 4;
    float* p_l   = (float*)(ws + o); o += (size_t)N_LIG * 4;
    float* p_t   = (float*)(ws + o); o += (size_t)N_TGT * 4;

    float* out = (float*)d_out;

    hipMemsetAsync(cnt_src, 0, zero_bytes, stream);

    k_fill<<<(NEDGE + 255) / 256, 256, 0, stream>>>(src, dst, cnt_src, cnt_dst, bsrc, bdst);
    k_prep<<<64, 256, 0, stream>>>(W2tl_r, Wt);
    k_prep1<<<DT / 16, 256, 0, stream>>>(W1lt_r, W1tl_l, Wt1);
    k_mt<<<(N_TGT * 8) / 256, 256, 0, stream>>>(x_l, bdst, cnt_dst, m_t);

    // conv1
    k_tgt1m<<<N_TGT / 16, 256, 0, stream>>>(x_t, Wt1, m_t, W1lt_l, b1lt, h_t, y_t1);
    k_hl<<<(N_LIG * 32) / 256, 256, 0, stream>>>(x_l, y_t1, bsrc, cnt_src,
                                                 W1tl_r, b1tl, hlb);

    // conv2 projections on the small (target) side
    k_tgt_gemm2<<<N_TGT / 8, 256, 0, stream>>>(h_t, W2tl_l, W2lt_r, y_t2, htW2r);

    // ligand-side neighbor mean of y_t2 (separate, latency-friendly gather)
    k_gl<<<(N_LIG * 32) / 256, 256, 0, stream>>>(y_t2, bsrc, cnt_src, gl2);

    // fused conv2 + predictor
    k_pt<<<N_TGT, 256, 0, stream>>>(hlb, bdst, cnt_dst, W2lt_l, b2lt, htW2r, Wp, p_t);
    k_pl<<<(N_LIG + 63) / 64, 256, 0, stream>>>(hlb, Wt, gl2, b2tl, Wp, p_l);

    // edges
    k_out<<<(NEDGE + 255) / 256, 256, 0, stream>>>(src, dst, p_l, p_t, bp, out);
}

// Round 6
// 152.733 us; speedup vs baseline: 1.5643x; 1.5643x over previous
//
#include <hip/hip_runtime.h>
#include <hip/hip_bf16.h>

#define N_LIG 100000
#define N_TGT 4000
#define NEDGE 150000
#define DT 1280
#define HD 128
#define CAP_L 32
#define CAP_T 128
#define NTILE_L 6250            // N_LIG / 16
#define NTILE_PAD 6252          // grid 1563 blocks x 4 tiles

typedef __attribute__((ext_vector_type(8))) short short8v;
typedef __attribute__((ext_vector_type(4))) float f32x4;

static __device__ __forceinline__ ushort f2bf(float f) {
    __hip_bfloat16 h = __float2bfloat16(f);
    union { __hip_bfloat16 h; ushort u; } c; c.h = h; return c.u;
}
static __device__ __forceinline__ float bf2f(ushort u) {
    union { unsigned v; float f; } c; c.v = ((unsigned)u) << 16; return c.f;
}

// ---------------------------------------------------------------------------
// K1: build adjacency buckets (int atomics only).
// ---------------------------------------------------------------------------
__global__ __launch_bounds__(256) void k_fill(
    const int* __restrict__ src, const int* __restrict__ dst,
    int* __restrict__ cnt_src, int* __restrict__ cnt_dst,
    int* __restrict__ bsrc, int* __restrict__ bdst)
{
    int e = blockIdx.x * 256 + threadIdx.x;
    if (e >= NEDGE) return;
    int s = src[e], d = dst[e];
    int ps = atomicAdd(&cnt_src[s], 1);
    if (ps < CAP_L) bsrc[(size_t)s * CAP_L + ps] = d;
    int pd = atomicAdd(&cnt_dst[d], 1);
    if (pd < CAP_T) bdst[(size_t)d * CAP_T + pd] = s;
}

// ---------------------------------------------------------------------------
// K1b: Wf = W2tl_r packed as MFMA B-fragments.
//   frag(ks,ct), lane(l15,g): us[j]=W[k][n], k=ks*32+g*4+j(+16), n=ct*16+l15
// ---------------------------------------------------------------------------
__global__ __launch_bounds__(256) void k_prep(
    const float* __restrict__ W, uint4* __restrict__ Wf)
{
    int gid = blockIdx.x * 256 + threadIdx.x;   // 2048
    int lane = gid & 63, frag = gid >> 6;       // frag 0..31
    int ks = frag >> 3, ct = frag & 7;
    int l15 = lane & 15, g = lane >> 4;
    int k = ks * 32 + g * 4, n = ct * 16 + l15;
    union { ushort us[8]; uint4 u; } o;
#pragma unroll
    for (int j = 0; j < 4; ++j) {
        o.us[j]     = f2bf(W[(size_t)(k + j) * HD + n]);
        o.us[4 + j] = f2bf(W[(size_t)(k + 16 + j) * HD + n]);
    }
    Wf[gid] = o.u;
}

// ---------------------------------------------------------------------------
// K1c: Wf1 = {W1lt_r | W1tl_l} packed as B-fragments (256 cols, K=1280).
//   frag(ks 0..39, nct 0..15)
// ---------------------------------------------------------------------------
__global__ __launch_bounds__(256) void k_prep1(
    const float* __restrict__ Wr,   // W1lt_r [1280,128]
    const float* __restrict__ Wl,   // W1tl_l [1280,128]
    uint4* __restrict__ Wf1)
{
    int gid = blockIdx.x * 256 + threadIdx.x;   // 40960
    int lane = gid & 63, frag = gid >> 6;       // 0..639
    int ks = frag >> 4, nct = frag & 15;
    int l15 = lane & 15, g = lane >> 4;
    int k = ks * 32 + g * 4, n = nct * 16 + l15;
    const float* Ws = (n < HD) ? Wr : Wl;
    int nn = n & 127;
    union { ushort us[8]; uint4 u; } o;
#pragma unroll
    for (int j = 0; j < 4; ++j) {
        o.us[j]     = f2bf(Ws[(size_t)(k + j) * HD + nn]);
        o.us[4 + j] = f2bf(Ws[(size_t)(k + 16 + j) * HD + nn]);
    }
    Wf1[gid] = o.u;
}

// ---------------------------------------------------------------------------
// K1e: xtf = x_t packed as bf16 A-fragments. frag(rt 0..249, ks 0..39)
// ---------------------------------------------------------------------------
__global__ __launch_bounds__(256) void k_prepx(
    const float* __restrict__ xt, uint4* __restrict__ xtf)
{
    int gid = blockIdx.x * 256 + threadIdx.x;   // 640000
    int lane = gid & 63, frag = gid >> 6;       // 0..9999
    int ks = frag % 40, rt = frag / 40;
    int row = rt * 16 + (lane & 15);
    int kb = ks * 32 + (lane >> 4) * 4;
    float4 a0 = *reinterpret_cast<const float4*>(xt + (size_t)row * DT + kb);
    float4 a1 = *reinterpret_cast<const float4*>(xt + (size_t)row * DT + kb + 16);
    union { ushort us[8]; uint4 u; } o;
    o.us[0] = f2bf(a0.x); o.us[1] = f2bf(a0.y); o.us[2] = f2bf(a0.z); o.us[3] = f2bf(a0.w);
    o.us[4] = f2bf(a1.x); o.us[5] = f2bf(a1.y); o.us[6] = f2bf(a1.z); o.us[7] = f2bf(a1.w);
    xtf[gid] = o.u;
}

// ---------------------------------------------------------------------------
// K1d: m_t[t][0..3] = mean_{src in bucket} x_l[src]
// ---------------------------------------------------------------------------
__global__ __launch_bounds__(256) void k_mt(
    const float* __restrict__ xl,
    const int* __restrict__ bdst, const int* __restrict__ cnt_dst,
    float* __restrict__ m_t)
{
    int t = blockIdx.x * 256 + threadIdx.x;
    int row = t >> 3, lane8 = t & 7;
    if (row >= N_TGT) return;
    int deg = cnt_dst[row];
    int n = min(deg, CAP_T);
    float4 acc = make_float4(0.f, 0.f, 0.f, 0.f);
    for (int i = lane8; i < n; i += 8) {
        int sid = bdst[(size_t)row * CAP_T + i];
        float4 x = *reinterpret_cast<const float4*>(xl + 4ull * (unsigned)sid);
        acc.x += x.x; acc.y += x.y; acc.z += x.z; acc.w += x.w;
    }
#pragma unroll
    for (int off = 1; off < 8; off <<= 1) {
        acc.x += __shfl_xor(acc.x, off); acc.y += __shfl_xor(acc.y, off);
        acc.z += __shfl_xor(acc.z, off); acc.w += __shfl_xor(acc.w, off);
    }
    if (lane8 == 0) {
        float dinv = 1.0f / fmaxf((float)deg, 1.0f);
        float4 o = make_float4(acc.x * dinv, acc.y * dinv, acc.z * dinv, acc.w * dinv);
        *reinterpret_cast<float4*>(m_t + 4 * row) = o;
    }
}

// ---------------------------------------------------------------------------
// K2: MFMA target conv1 — all operand loads 16B coalesced from packed frags.
// ---------------------------------------------------------------------------
__global__ __launch_bounds__(256) void k_tgt1m(
    const uint4* __restrict__ xtf,    // [250*40][64] bf16 A-frags
    const uint4* __restrict__ Wf1,    // [640][64] bf16 B-frags
    const float* __restrict__ m_t,    // [4000,4]
    const float* __restrict__ W1lt_l, // [4,128]
    const float* __restrict__ b1lt,
    float* __restrict__ h_t, float* __restrict__ y_t1)
{
    int w = threadIdx.x >> 6;
    int lane = threadIdx.x & 63;
    int l15 = lane & 15, g = lane >> 4;
    int rt = blockIdx.x;
    int row0 = rt * 16;
    int cb = w * 64;

    f32x4 acc[4];
#pragma unroll
    for (int ct = 0; ct < 4; ++ct) acc[ct] = (f32x4){0.f, 0.f, 0.f, 0.f};

    for (int ks = 0; ks < DT / 32; ++ks) {
        union { uint4 u; short8v s; } ua;
        ua.u = xtf[(size_t)(rt * 40 + ks) * 64 + lane];
#pragma unroll
        for (int ct = 0; ct < 4; ++ct) {
            int nct = w * 4 + ct;
            union { uint4 u; short8v s; } ub;
            ub.u = Wf1[(size_t)(ks * 16 + nct) * 64 + lane];
            acc[ct] = __builtin_amdgcn_mfma_f32_16x16x32_bf16(ua.s, ub.s, acc[ct], 0, 0, 0);
        }
    }

    if (w < 2) {
#pragma unroll
        for (int ct = 0; ct < 4; ++ct) {
            int c = cb + ct * 16 + l15;
            float wl0 = W1lt_l[c], wl1 = W1lt_l[HD + c],
                  wl2 = W1lt_l[2 * HD + c], wl3 = W1lt_l[3 * HD + c];
            float bb = b1lt[c];
#pragma unroll
            for (int j = 0; j < 4; ++j) {
                int grow = row0 + 4 * g + j;
                float4 m = *reinterpret_cast<const float4*>(m_t + 4 * grow);
                float v = acc[ct][j] + bb + m.x * wl0 + m.y * wl1 + m.z * wl2 + m.w * wl3;
                h_t[(size_t)grow * HD + c] = fmaxf(v, 0.0f);
            }
        }
    } else {
#pragma unroll
        for (int ct = 0; ct < 4; ++ct) {
            int c = cb - HD + ct * 16 + l15;
#pragma unroll
            for (int j = 0; j < 4; ++j) {
                int grow = row0 + 4 * g + j;
                y_t1[(size_t)grow * HD + c] = acc[ct][j];
            }
        }
    }
}

// ---------------------------------------------------------------------------
// K3: fused ligand conv1 -> hlb (row layout, for k_pt) + hlbf (fragment
// layout, for k_pl). Block = one 16-row tile; 16 threads per node, thread
// tc = (ks,g) owns cols ks*32+g*4+{0..3} and +16..+19 (one full A-fragment).
// ---------------------------------------------------------------------------
__global__ __launch_bounds__(256) void k_hl(
    const float* __restrict__ xl, const float* __restrict__ y_t1,
    const int* __restrict__ bsrc, const int* __restrict__ cnt_src,
    const float* __restrict__ W1tl_r,  // [4,128]
    const float* __restrict__ b1tl,
    ushort* __restrict__ hlb, uint4* __restrict__ hlbf)
{
    int tc = threadIdx.x & 15;
    int node = blockIdx.x * 16 + (threadIdx.x >> 4);
    int ks = tc >> 2, g = tc & 3;
    int kb = ks * 32 + g * 4;

    int deg = cnt_src[node];
    int n = min(deg, CAP_L);
    float4 s0 = make_float4(0.f, 0.f, 0.f, 0.f);
    float4 s1 = make_float4(0.f, 0.f, 0.f, 0.f);
    for (int i = 0; i < n; ++i) {
        int did = bsrc[(size_t)node * CAP_L + i];
        float4 v0 = *reinterpret_cast<const float4*>(y_t1 + (size_t)did * HD + kb);
        float4 v1 = *reinterpret_cast<const float4*>(y_t1 + (size_t)did * HD + kb + 16);
        s0.x += v0.x; s0.y += v0.y; s0.z += v0.z; s0.w += v0.w;
        s1.x += v1.x; s1.y += v1.y; s1.z += v1.z; s1.w += v1.w;
    }
    float dinv = 1.0f / fmaxf((float)deg, 1.0f);
    float4 x = *reinterpret_cast<const float4*>(xl + 4ull * (unsigned)node);

    float4 b0 = *reinterpret_cast<const float4*>(b1tl + kb);
    float4 b1 = *reinterpret_cast<const float4*>(b1tl + kb + 16);
    float4 wa0 = *reinterpret_cast<const float4*>(W1tl_r + 0 * HD + kb);
    float4 wa1 = *reinterpret_cast<const float4*>(W1tl_r + 1 * HD + kb);
    float4 wa2 = *reinterpret_cast<const float4*>(W1tl_r + 2 * HD + kb);
    float4 wa3 = *reinterpret_cast<const float4*>(W1tl_r + 3 * HD + kb);
    float4 wb0 = *reinterpret_cast<const float4*>(W1tl_r + 0 * HD + kb + 16);
    float4 wb1 = *reinterpret_cast<const float4*>(W1tl_r + 1 * HD + kb + 16);
    float4 wb2 = *reinterpret_cast<const float4*>(W1tl_r + 2 * HD + kb + 16);
    float4 wb3 = *reinterpret_cast<const float4*>(W1tl_r + 3 * HD + kb + 16);

    union { ushort us[8]; uint4 u; ushort4 h[2]; } o;
    o.us[0] = f2bf(fmaxf(s0.x * dinv + b0.x + x.x * wa0.x + x.y * wa1.x + x.z * wa2.x + x.w * wa3.x, 0.f));
    o.us[1] = f2bf(fmaxf(s0.y * dinv + b0.y + x.x * wa0.y + x.y * wa1.y + x.z * wa2.y + x.w * wa3.y, 0.f));
    o.us[2] = f2bf(fmaxf(s0.z * dinv + b0.z + x.x * wa0.z + x.y * wa1.z + x.z * wa2.z + x.w * wa3.z, 0.f));
    o.us[3] = f2bf(fmaxf(s0.w * dinv + b0.w + x.x * wa0.w + x.y * wa1.w + x.z * wa2.w + x.w * wa3.w, 0.f));
    o.us[4] = f2bf(fmaxf(s1.x * dinv + b1.x + x.x * wb0.x + x.y * wb1.x + x.z * wb2.x + x.w * wb3.x, 0.f));
    o.us[5] = f2bf(fmaxf(s1.y * dinv + b1.y + x.x * wb0.y + x.y * wb1.y + x.z * wb2.y + x.w * wb3.y, 0.f));
    o.us[6] = f2bf(fmaxf(s1.z * dinv + b1.z + x.x * wb0.z + x.y * wb1.z + x.z * wb2.z + x.w * wb3.z, 0.f));
    o.us[7] = f2bf(fmaxf(s1.w * dinv + b1.w + x.x * wb0.w + x.y * wb1.w + x.z * wb2.w + x.w * wb3.w, 0.f));

    *reinterpret_cast<ushort4*>(hlb + (size_t)node * HD + kb)      = o.h[0];
    *reinterpret_cast<ushort4*>(hlb + (size_t)node * HD + kb + 16) = o.h[1];
    int lane = (node & 15) + 16 * g;
    hlbf[(size_t)(blockIdx.x * 4 + ks) * 64 + lane] = o.u;
}

// ---------------------------------------------------------------------------
// K4: h_t [4000,128] @ {W2tl_l, W2lt_r} -> y_t2, htW2r
// ---------------------------------------------------------------------------
__global__ __launch_bounds__(256) void k_tgt_gemm2(
    const float* __restrict__ ht,
    const float* __restrict__ Wl,   // W2tl_l [128,128]
    const float* __restrict__ Wr,   // W2lt_r [128,128]
    float* __restrict__ y_t2,
    float* __restrict__ htW2r)
{
    __shared__ float xs[8][HD];
    int row0 = blockIdx.x * 8;
    const float4* srcv = reinterpret_cast<const float4*>(ht + (size_t)row0 * HD);
    float4* dstv = reinterpret_cast<float4*>(&xs[0][0]);
    for (int i = threadIdx.x; i < 8 * HD / 4; i += 256) dstv[i] = srcv[i];
    __syncthreads();

    int n = threadIdx.x;
    const float* W = (n < HD) ? (Wl + n) : (Wr + (n - HD));
    float acc[8] = {0.f,0.f,0.f,0.f,0.f,0.f,0.f,0.f};
    for (int k = 0; k < HD; k += 4) {
        float w0 = W[(size_t)(k + 0) * HD];
        float w1 = W[(size_t)(k + 1) * HD];
        float w2 = W[(size_t)(k + 2) * HD];
        float w3 = W[(size_t)(k + 3) * HD];
#pragma unroll
        for (int r = 0; r < 8; ++r) {
            float4 a = *reinterpret_cast<const float4*>(&xs[r][k]);
            acc[r] += a.x * w0 + a.y * w1 + a.z * w2 + a.w * w3;
        }
    }
    float* o = (n < HD) ? (y_t2 + (size_t)row0 * HD + n)
                        : (htW2r + (size_t)row0 * HD + (n - HD));
#pragma unroll
    for (int r = 0; r < 8; ++r) o[(size_t)r * HD] = acc[r];
}

// ---------------------------------------------------------------------------
// K5: fused target conv2 + predictor (two-phase gather + GEMM column phase)
// ---------------------------------------------------------------------------
__global__ __launch_bounds__(256) void k_pt(
    const ushort* __restrict__ hlb,
    const int* __restrict__ bdst, const int* __restrict__ cnt_dst,
    const float* __restrict__ W,    // W2lt_l [128,128]
    const float* __restrict__ b,    // b2lt
    const float* __restrict__ htW2r,
    const float* __restrict__ Wp,   // [256]
    float* __restrict__ p_t)
{
    __shared__ float sm[8][HD];
    __shared__ float msh[HD];
    __shared__ float sum2[2];
    int row = blockIdx.x;
    int wg = threadIdx.x >> 5, c = threadIdx.x & 31;
    int deg = cnt_dst[row];
    int nn = min(deg, CAP_T);

    float4 s = make_float4(0.f, 0.f, 0.f, 0.f);
    for (int i = wg; i < nn; i += 8) {
        int sid = bdst[(size_t)row * CAP_T + i];
        ushort4 v = *reinterpret_cast<const ushort4*>(hlb + (size_t)sid * HD + c * 4);
        s.x += bf2f(v.x); s.y += bf2f(v.y); s.z += bf2f(v.z); s.w += bf2f(v.w);
    }
    *reinterpret_cast<float4*>(&sm[wg][c * 4]) = s;
    __syncthreads();

    if (threadIdx.x < HD) {
        int h = threadIdx.x;
        float dinv = 1.0f / fmaxf((float)deg, 1.0f);
        float acc = sm[0][h] + sm[1][h] + sm[2][h] + sm[3][h]
                  + sm[4][h] + sm[5][h] + sm[6][h] + sm[7][h];
        msh[h] = acc * dinv;
    }
    __syncthreads();

    if (threadIdx.x < HD) {
        int h = threadIdx.x;
        float g = 0.f;
        for (int k = 0; k < HD; k += 4) {
            float4 mk = *reinterpret_cast<const float4*>(&msh[k]);
            g += mk.x * W[(size_t)(k + 0) * HD + h] + mk.y * W[(size_t)(k + 1) * HD + h]
               + mk.z * W[(size_t)(k + 2) * HD + h] + mk.w * W[(size_t)(k + 3) * HD + h];
        }
        float v = fmaxf(g + b[h] + htW2r[(size_t)row * HD + h], 0.0f);
        float part = v * Wp[HD + h];
#pragma unroll
        for (int off = 1; off < 64; off <<= 1) part += __shfl_xor(part, off);
        if ((h & 63) == 0) sum2[h >> 6] = part;
    }
    __syncthreads();
    if (threadIdx.x == 0) p_t[row] = sum2[0] + sum2[1];
}

// ---------------------------------------------------------------------------
// K6: ligand conv2 + predictor via MFMA; A/B fully coalesced from packed
// fragments; fused y_t2 neighbor-mean epilogue (L2-resident, measured free).
// ---------------------------------------------------------------------------
__global__ __launch_bounds__(256) void k_pl(
    const uint4* __restrict__ hlbf,   // [NTILE_PAD*4][64] A-frags
    const uint4* __restrict__ Wf,     // [32][64] B-frags
    const float* __restrict__ y_t2,
    const int* __restrict__ bsrc, const int* __restrict__ cnt_src,
    const float* __restrict__ b,      // b2tl
    const float* __restrict__ Wp,     // [256]; ligand part = Wp[0..127]
    float* __restrict__ p_l)
{
    int wid = threadIdx.x >> 6;
    int lane = threadIdx.x & 63;
    int l15 = lane & 15, g = lane >> 4;
    int tile = blockIdx.x * 4 + wid;
    int wrow0 = tile * 16;

    f32x4 acc[8];
#pragma unroll
    for (int ct = 0; ct < 8; ++ct) acc[ct] = (f32x4){0.f, 0.f, 0.f, 0.f};

#pragma unroll
    for (int ks = 0; ks < 4; ++ks) {
        union { uint4 u; short8v s; } ua;
        ua.u = hlbf[(size_t)(tile * 4 + ks) * 64 + lane];
#pragma unroll
        for (int ct = 0; ct < 8; ++ct) {
            union { uint4 u; short8v s; } ub;
            ub.u = Wf[(ks * 8 + ct) * 64 + lane];
            acc[ct] = __builtin_amdgcn_mfma_f32_16x16x32_bf16(ua.s, ub.s, acc[ct], 0, 0, 0);
        }
    }

    float wpv[8], bv[8];
#pragma unroll
    for (int ct = 0; ct < 8; ++ct) {
        int c = ct * 16 + l15;
        wpv[ct] = Wp[c];
        bv[ct]  = b[c];
    }

#pragma unroll
    for (int j = 0; j < 4; ++j) {
        int row = wrow0 + g * 4 + j;
        bool valid = row < N_LIG;
        int deg = valid ? cnt_src[row] : 0;
        int nn = min(deg, CAP_L);
        float dinv = 1.0f / fmaxf((float)deg, 1.0f);
        float s[8];
#pragma unroll
        for (int ct = 0; ct < 8; ++ct) s[ct] = 0.f;
        for (int i = 0; i < nn; ++i) {
            int did = bsrc[(size_t)row * CAP_L + i];
            const float* yp = y_t2 + (size_t)did * HD + l15;
#pragma unroll
            for (int ct = 0; ct < 8; ++ct) s[ct] += yp[ct * 16];
        }
        float part = 0.f;
#pragma unroll
        for (int ct = 0; ct < 8; ++ct) {
            float v = acc[ct][j] + s[ct] * dinv + bv[ct];
            part += fmaxf(v, 0.f) * wpv[ct];
        }
#pragma unroll
        for (int off = 1; off < 16; off <<= 1) part += __shfl_xor(part, off);
        if (valid && l15 == 0) p_l[row] = part;
    }
}

// ---------------------------------------------------------------------------
// K7: out[e] = p_l[src[e]] + p_t[dst[e]] + bp
// ---------------------------------------------------------------------------
__global__ __launch_bounds__(256) void k_out(
    const int* __restrict__ src, const int* __restrict__ dst,
    const float* __restrict__ p_l, const float* __restrict__ p_t,
    const float* __restrict__ bp, float* __restrict__ out)
{
    int e = blockIdx.x * 256 + threadIdx.x;
    if (e >= NEDGE) return;
    out[e] = p_l[src[e]] + p_t[dst[e]] + bp[0];
}

// ---------------------------------------------------------------------------
extern "C" void kernel_launch(void* const* d_in, const int* in_sizes, int n_in,
                              void* d_out, int out_size, void* d_ws, size_t ws_size,
                              hipStream_t stream)
{
    const float* x_l    = (const float*)d_in[0];
    const float* x_t    = (const float*)d_in[1];
    const int*   ei     = (const int*)  d_in[2];
    const float* W1lt_l = (const float*)d_in[3];
    const float* b1lt   = (const float*)d_in[4];
    const float* W1lt_r = (const float*)d_in[5];
    const float* W1tl_l = (const float*)d_in[6];
    const float* b1tl   = (const float*)d_in[7];
    const float* W1tl_r = (const float*)d_in[8];
    const float* W2lt_l = (const float*)d_in[9];
    const float* b2lt   = (const float*)d_in[10];
    const float* W2lt_r = (const float*)d_in[11];
    const float* W2tl_l = (const float*)d_in[12];
    const float* b2tl   = (const float*)d_in[13];
    const float* W2tl_r = (const float*)d_in[14];
    const float* Wp     = (const float*)d_in[15];
    const float* bp     = (const float*)d_in[16];

    const int* src = ei;            // ligand indices
    const int* dst = ei + NEDGE;    // target indices

    char* ws = (char*)d_ws;
    size_t o = 0;
    int* cnt_src = (int*)(ws + o); o += (size_t)N_LIG * 4;
    int* cnt_dst = (int*)(ws + o); o += (size_t)N_TGT * 4;
    size_t zero_bytes = o;
    int* bsrc = (int*)(ws + o); o += (size_t)N_LIG * CAP_L * 4;
    int* bdst = (int*)(ws + o); o += (size_t)N_TGT * CAP_T * 4;
    ushort* hlb  = (ushort*)(ws + o); o += (size_t)N_LIG * HD * 2;
    uint4* hlbf  = (uint4*)(ws + o);  o += (size_t)NTILE_PAD * 4 * 64 * 16;
    uint4* Wf    = (uint4*)(ws + o);  o += (size_t)32 * 64 * 16;
    uint4* Wf1   = (uint4*)(ws + o);  o += (size_t)640 * 64 * 16;
    uint4* xtf   = (uint4*)(ws + o);  o += (size_t)10000 * 64 * 16;
    float* m_t   = (float*)(ws + o); o += (size_t)N_TGT * 4 * 4;
    float* y_t1  = (float*)(ws + o); o += (size_t)N_TGT * HD * 4;
    float* h_t   = (float*)(ws + o); o += (size_t)N_TGT * HD * 4;
    float* y_t2  = (float*)(ws + o); o += (size_t)N_TGT * HD * 4;
    float* htW2r = (float*)(ws + o); o += (size_t)N_TGT * HD * 4;
    float* p_l   = (float*)(ws + o); o += (size_t)N_LIG * 4;
    float* p_t   = (float*)(ws + o); o += (size_t)N_TGT * 4;

    float* out = (float*)d_out;

    hipMemsetAsync(cnt_src, 0, zero_bytes, stream);

    k_fill<<<(NEDGE + 255) / 256, 256, 0, stream>>>(src, dst, cnt_src, cnt_dst, bsrc, bdst);
    k_prep<<<8, 256, 0, stream>>>(W2tl_r, Wf);
    k_prep1<<<160, 256, 0, stream>>>(W1lt_r, W1tl_l, Wf1);
    k_prepx<<<2500, 256, 0, stream>>>(x_t, xtf);
    k_mt<<<(N_TGT * 8) / 256, 256, 0, stream>>>(x_l, bdst, cnt_dst, m_t);

    // conv1
    k_tgt1m<<<N_TGT / 16, 256, 0, stream>>>(xtf, Wf1, m_t, W1lt_l, b1lt, h_t, y_t1);
    k_hl<<<NTILE_L, 256, 0, stream>>>(x_l, y_t1, bsrc, cnt_src, W1tl_r, b1tl, hlb, hlbf);

    // conv2 projections on the small (target) side
    k_tgt_gemm2<<<N_TGT / 8, 256, 0, stream>>>(h_t, W2tl_l, W2lt_r, y_t2, htW2r);

    // fused conv2 + predictor
    k_pt<<<N_TGT, 256, 0, stream>>>(hlb, bdst, cnt_dst, W2lt_l, b2lt, htW2r, Wp, p_t);
    k_pl<<<(NTILE_L + 3) / 4, 256, 0, stream>>>(hlbf, Wf, y_t2, bsrc, cnt_src,
                                                b2tl, Wp, p_l);

    // edges
    k_out<<<(NEDGE + 255) / 256, 256, 0, stream>>>(src, dst, p_l, p_t, bp, out);
}